// Round 1
// baseline (1091.954 us; speedup 1.0000x reference)
//
#include <hip/hip_runtime.h>
#include <hip/hip_bf16.h>

#define HID   256
#define NGATE 1024
#define INP   72
#define INPP  96
#define STEPS 8
#define TB    32      // batch rows per block (was 64)
#define NTHR  256     // 4 waves per block (was 512/8) -> 2 independent blocks/CU
#define LDH   264     // h_lds row stride (bf16 elems): 256 + 8 pad
#define LDX   104     // x_lds row stride: 96 + 8 pad

// ws layout (bf16/ushort element offsets) -- unchanged from previous version
#define OFF_WHH 0
#define OFF_WIH 262144   // 1024*256
#define OFF_WH  360448   // + 1024*96
#define OFF_WC  425984   // + 256*256
#define OFF_WO  491520   // + 256*256
#define N_BF    512000   // + 80*256
#define OFF_BG_BYTES 1024000
#define OFF_STAGE_BYTES (1u << 20)

typedef short  s8_t  __attribute__((ext_vector_type(8)));
typedef float  f4_t  __attribute__((ext_vector_type(4)));

static __device__ __forceinline__ unsigned short f2bf(float f) {
  unsigned int u = __float_as_uint(f);
  u = (u + 0x7FFFu + ((u >> 16) & 1u)) >> 16;   // RNE
  return (unsigned short)u;
}
static __device__ __forceinline__ float fast_rcp(float x) {
#if __has_builtin(__builtin_amdgcn_rcpf)
  return __builtin_amdgcn_rcpf(x);
#else
  return 1.f / x;
#endif
}
static __device__ __forceinline__ float sigm(float x) {
  return fast_rcp(1.f + __expf(-x));
}
static __device__ __forceinline__ float tanh_(float x) {
  float t = fminf(-2.f * x, 88.f);
  float e = __expf(t);
  return (1.f - e) * fast_rcp(1.f + e);
}

__global__ void prep_kernel(const float* __restrict__ Wih, const float* __restrict__ Whh,
                            const float* __restrict__ bih, const float* __restrict__ bhh,
                            const float* __restrict__ Wh, const float* __restrict__ Wc,
                            const float* __restrict__ Wo,
                            unsigned short* __restrict__ wsh, float* __restrict__ bg) {
  int stride = gridDim.x * blockDim.x;
  for (int i = blockIdx.x * blockDim.x + threadIdx.x; i < N_BF + NGATE; i += stride) {
    if (i < OFF_WIH) {
      wsh[i] = f2bf(Whh[i]);
    } else if (i < OFF_WH) {
      int j = i - OFF_WIH; int n = j / INPP; int k = j - n * INPP;
      wsh[i] = (k < INP) ? f2bf(Wih[n * INP + k]) : (unsigned short)0;
    } else if (i < OFF_WC) {
      wsh[i] = f2bf(Wh[i - OFF_WH]);
    } else if (i < OFF_WO) {
      wsh[i] = f2bf(Wc[i - OFF_WC]);
    } else if (i < N_BF) {
      int j = i - OFF_WO; int t = j >> 8; int k = j & 255;
      wsh[i] = (t < INP) ? f2bf(Wo[t * HID + k]) : (unsigned short)0;
    } else {
      int j = i - N_BF;
      bg[j] = bih[j] + bhh[j];
    }
  }
}

// Block: 256 threads = 4 waves, owns TB=32 batch rows for the whole recurrence.
// Wave w owns gate cols [w*64, w*64+64) inside EACH of the 4 gate quadrants
// (ct = 0..3 tiles of 16). Per-wave register footprint is the same as the old
// 512-thread version (~256 combined VGPR+AGPR -> 2 waves/SIMD), but blocks are
// half-sized so TWO INDEPENDENT blocks co-reside per CU: one block's VALU cell
// update / barrier drain overlaps the other block's MFMA phase.
template <int STAGED>
__global__ __launch_bounds__(NTHR, 2) void lstm_kernel(
    const float* __restrict__ z, const unsigned short* __restrict__ wsh,
    const float* __restrict__ bg, const float* __restrict__ bh,
    const float* __restrict__ bc, const float* __restrict__ bo,
    float* __restrict__ out, float* __restrict__ stage, int NB) {
  __shared__ unsigned short h_lds[TB * LDH];
  __shared__ unsigned short x_lds[TB * LDX];

  const int tid  = threadIdx.x;
  const int w    = tid >> 6;     // wave 0..3
  const int lane = tid & 63;
  const int lq   = lane >> 4;    // quad 0..3
  const int ln   = lane & 15;
  const int rb   = blockIdx.x * TB;
  const int colh0 = w * 64 + ln; // wave's hidden-col base (+ct*16, ct=0..3)

  // lane-varying bases (compile-time offsets applied at each unrolled use)
  const unsigned short* whh_l = wsh + OFF_WHH + colh0 * HID  + lq * 8;
  const unsigned short* wih_l = wsh + OFF_WIH + colh0 * INPP + lq * 8;
  const unsigned short* wh_l  = wsh + OFF_WH  + colh0 * HID  + lq * 8;
  const unsigned short* wc_l  = wsh + OFF_WC  + colh0 * HID  + lq * 8;
  const unsigned short* h_rd  = &h_lds[ln * LDH + lq * 8];
  const unsigned short* x_rd  = &x_lds[ln * LDX + lq * 8];
  unsigned short*       h_wr  = &h_lds[(lq * 4) * LDH + colh0];

  // x starts as zeros (incl. pad cols 72..95)
  for (int i = tid; i < TB * LDX; i += NTHR) x_lds[i] = 0;

  // ---------------- init: h = z0@Wh^T + bh, c = z0@Wc^T + bc ----------------
  f4_t acc_h[2][4], acc_c[2][4];
  #pragma unroll
  for (int rt = 0; rt < 2; ++rt)
    #pragma unroll
    for (int ct = 0; ct < 4; ++ct) {
      acc_h[rt][ct] = {0.f, 0.f, 0.f, 0.f};
      acc_c[rt][ct] = {0.f, 0.f, 0.f, 0.f};
    }

  const float* z_l = z + (size_t)(rb + ln) * HID + lq * 8;

  #pragma unroll 2
  for (int kc = 0; kc < 8; ++kc) {
    s8_t a[2];
    #pragma unroll
    for (int rt = 0; rt < 2; ++rt) {
      f4_t v0 = *reinterpret_cast<const f4_t*>(z_l + rt * 16 * HID + kc * 32);
      f4_t v1 = *reinterpret_cast<const f4_t*>(z_l + rt * 16 * HID + kc * 32 + 4);
      s8_t av;
      av[0] = (short)f2bf(v0[0]); av[1] = (short)f2bf(v0[1]);
      av[2] = (short)f2bf(v0[2]); av[3] = (short)f2bf(v0[3]);
      av[4] = (short)f2bf(v1[0]); av[5] = (short)f2bf(v1[1]);
      av[6] = (short)f2bf(v1[2]); av[7] = (short)f2bf(v1[3]);
      a[rt] = av;
    }
    #pragma unroll
    for (int ct = 0; ct < 4; ++ct) {
      s8_t bhf = *reinterpret_cast<const s8_t*>(wh_l + ct * 16 * HID + kc * 32);
      s8_t bcf = *reinterpret_cast<const s8_t*>(wc_l + ct * 16 * HID + kc * 32);
      #pragma unroll
      for (int rt = 0; rt < 2; ++rt) {
        acc_h[rt][ct] = __builtin_amdgcn_mfma_f32_16x16x32_bf16(a[rt], bhf, acc_h[rt][ct], 0, 0, 0);
        acc_c[rt][ct] = __builtin_amdgcn_mfma_f32_16x16x32_bf16(a[rt], bcf, acc_c[rt][ct], 0, 0, 0);
      }
    }
  }

  float c_reg[2][4][4];
  #pragma unroll
  for (int ct = 0; ct < 4; ++ct) {
    const float bhv = bh[colh0 + ct * 16];
    const float bcv = bc[colh0 + ct * 16];
    #pragma unroll
    for (int rt = 0; rt < 2; ++rt)
      #pragma unroll
      for (int r = 0; r < 4; ++r) {
        float hv = acc_h[rt][ct][r] + bhv;
        c_reg[rt][ct][r] = acc_c[rt][ct][r] + bcv;
        h_wr[(rt * 16 + r) * LDH + ct * 16] = f2bf(hv);
      }
  }
  __syncthreads();

  float biasg[4][4];
  #pragma unroll
  for (int q = 0; q < 4; ++q)
    #pragma unroll
    for (int ct = 0; ct < 4; ++ct)
      biasg[q][ct] = bg[q * 256 + colh0 + ct * 16];

  // y tiles: wave w owns cols [w*16, w*16+16) (all < 72); wave 0 also owns
  // the remainder tile cols [64,80) (valid < 72)
  const int colY = w * 16 + ln;
  const float bov = bo[colY];
  const unsigned short* wo_l  = wsh + OFF_WO + colY * HID + lq * 8;
  const int colY2 = 64 + ln;
  const float bov2 = (colY2 < INP) ? bo[colY2] : 0.f;
  const unsigned short* wo2_l = wsh + OFF_WO + colY2 * HID + lq * 8;

  for (int s = 0; s < STEPS; ++s) {
    f4_t acc[4][2][4];                     // [quadrant][row-tile][col-tile]
    #pragma unroll
    for (int q = 0; q < 4; ++q)
      #pragma unroll
      for (int rt = 0; rt < 2; ++rt)
        #pragma unroll
        for (int ct = 0; ct < 4; ++ct) {
          const float b = biasg[q][ct];
          acc[q][rt][ct] = {b, b, b, b};
        }

    // gates += h @ W_hh^T   (K = 256)
    #pragma unroll 2
    for (int kc = 0; kc < 8; ++kc) {
      s8_t a[2];
      #pragma unroll
      for (int rt = 0; rt < 2; ++rt)
        a[rt] = *reinterpret_cast<const s8_t*>(h_rd + rt * 16 * LDH + kc * 32);
      #pragma unroll
      for (int q = 0; q < 4; ++q)
        #pragma unroll
        for (int ct = 0; ct < 4; ++ct) {
          s8_t bfr = *reinterpret_cast<const s8_t*>(whh_l + (q * 256 + ct * 16) * HID + kc * 32);
          #pragma unroll
          for (int rt = 0; rt < 2; ++rt)
            acc[q][rt][ct] = __builtin_amdgcn_mfma_f32_16x16x32_bf16(a[rt], bfr, acc[q][rt][ct], 0, 0, 0);
        }
    }
    // gates += x @ W_ih^T   (K = 96 padded; Wih pad cols are zero)
    #pragma unroll
    for (int kc = 0; kc < 3; ++kc) {
      s8_t a[2];
      #pragma unroll
      for (int rt = 0; rt < 2; ++rt)
        a[rt] = *reinterpret_cast<const s8_t*>(x_rd + rt * 16 * LDX + kc * 32);
      #pragma unroll
      for (int q = 0; q < 4; ++q)
        #pragma unroll
        for (int ct = 0; ct < 4; ++ct) {
          s8_t bfr = *reinterpret_cast<const s8_t*>(wih_l + (q * 256 + ct * 16) * INPP + kc * 32);
          #pragma unroll
          for (int rt = 0; rt < 2; ++rt)
            acc[q][rt][ct] = __builtin_amdgcn_mfma_f32_16x16x32_bf16(a[rt], bfr, acc[q][rt][ct], 0, 0, 0);
        }
    }
    __syncthreads();   // all h_lds/x_lds reads done

    // lane-local LSTM cell update; write new h (bf16) to LDS
    #pragma unroll
    for (int rt = 0; rt < 2; ++rt)
      #pragma unroll
      for (int ct = 0; ct < 4; ++ct)
        #pragma unroll
        for (int r = 0; r < 4; ++r) {
          float iv = sigm(acc[0][rt][ct][r]);
          float fv = sigm(acc[1][rt][ct][r]);
          float gv = tanh_(acc[2][rt][ct][r]);
          float ov = sigm(acc[3][rt][ct][r]);
          float cn = fv * c_reg[rt][ct][r] + iv * gv;
          c_reg[rt][ct][r] = cn;
          float hv = ov * tanh_(cn);
          h_wr[(rt * 16 + r) * LDH + ct * 16] = f2bf(hv);
        }
    __syncthreads();   // new h visible to all waves

    // y = sigmoid(h_new @ Wo^T + bo); store (staged or direct), feed back as x
    {
      f4_t accy[2];
      #pragma unroll
      for (int rt = 0; rt < 2; ++rt) accy[rt] = {bov, bov, bov, bov};
      #pragma unroll 2
      for (int kc = 0; kc < 8; ++kc) {
        s8_t bfr = *reinterpret_cast<const s8_t*>(wo_l + kc * 32);
        #pragma unroll
        for (int rt = 0; rt < 2; ++rt) {
          s8_t a = *reinterpret_cast<const s8_t*>(h_rd + rt * 16 * LDH + kc * 32);
          accy[rt] = __builtin_amdgcn_mfma_f32_16x16x32_bf16(a, bfr, accy[rt], 0, 0, 0);
        }
      }
      float* st_base;
      if (STAGED) {
        st_base = stage + (((size_t)s * NB + blockIdx.x) * TB + lq * 4) * INP + colY;
      } else {
        st_base = out + (size_t)(rb + lq * 4) * (STEPS * INP) + s * INP + colY;
      }
      unsigned short* x_wr = &x_lds[(lq * 4) * LDX + colY];
      #pragma unroll
      for (int rt = 0; rt < 2; ++rt)
        #pragma unroll
        for (int r = 0; r < 4; ++r) {
          float yv = sigm(accy[rt][r]);
          if (STAGED) {
            st_base[(size_t)(rt * 16 + r) * INP] = yv;
          } else {
            st_base[(size_t)(rt * 16 + r) * (STEPS * INP)] = yv;
          }
          x_wr[(rt * 16 + r) * LDX] = f2bf(yv);
        }
    }
    if (w == 0) {   // remainder y tile, cols 64..71
      f4_t accy[2];
      #pragma unroll
      for (int rt = 0; rt < 2; ++rt) accy[rt] = {bov2, bov2, bov2, bov2};
      #pragma unroll 2
      for (int kc = 0; kc < 8; ++kc) {
        s8_t bfr = *reinterpret_cast<const s8_t*>(wo2_l + kc * 32);
        #pragma unroll
        for (int rt = 0; rt < 2; ++rt) {
          s8_t a = *reinterpret_cast<const s8_t*>(h_rd + rt * 16 * LDH + kc * 32);
          accy[rt] = __builtin_amdgcn_mfma_f32_16x16x32_bf16(a, bfr, accy[rt], 0, 0, 0);
        }
      }
      if (colY2 < INP) {
        float* st_base;
        if (STAGED) {
          st_base = stage + (((size_t)s * NB + blockIdx.x) * TB + lq * 4) * INP + colY2;
        } else {
          st_base = out + (size_t)(rb + lq * 4) * (STEPS * INP) + s * INP + colY2;
        }
        unsigned short* x_wr = &x_lds[(lq * 4) * LDX + colY2];
        #pragma unroll
        for (int rt = 0; rt < 2; ++rt)
          #pragma unroll
          for (int r = 0; r < 4; ++r) {
            float yv = sigm(accy[rt][r]);
            if (STAGED) {
              st_base[(size_t)(rt * 16 + r) * INP] = yv;
            } else {
              st_base[(size_t)(rt * 16 + r) * (STEPS * INP)] = yv;
            }
            x_wr[(rt * 16 + r) * LDX] = f2bf(yv);
          }
      }
    }
    __syncthreads();   // x_lds writes done before next step's reads
  }
}

// stage[((s*NB + b)*TB + r)*72 + c]  ->  out[(b*TB + r)*576 + s*72 + c]
__global__ __launch_bounds__(512) void reorder_kernel(
    const float* __restrict__ stage, float* __restrict__ out, int NB) {
  const int lane = threadIdx.x & 63;
  const int row  = blockIdx.x * 8 + (threadIdx.x >> 6);   // global batch row
  const int b    = row >> 5;          // TB=32
  const int r    = row & 31;
  #pragma unroll
  for (int i = lane; i < STEPS * INP; i += 64) {
    int s = i / INP;
    int c = i - s * INP;
    out[(size_t)row * (STEPS * INP) + i] =
        stage[(((size_t)s * NB + b) * TB + r) * INP + c];
  }
}

extern "C" void kernel_launch(void* const* d_in, const int* in_sizes, int n_in,
                              void* d_out, int out_size, void* d_ws, size_t ws_size,
                              hipStream_t stream) {
  const float* z   = (const float*)d_in[0];
  const float* Wih = (const float*)d_in[1];
  const float* Whh = (const float*)d_in[2];
  const float* bih = (const float*)d_in[3];
  const float* bhh = (const float*)d_in[4];
  const float* Wh  = (const float*)d_in[5];
  const float* bh  = (const float*)d_in[6];
  const float* Wc  = (const float*)d_in[7];
  const float* bc  = (const float*)d_in[8];
  const float* Wo  = (const float*)d_in[9];
  const float* bo  = (const float*)d_in[10];
  float* out = (float*)d_out;

  unsigned short* wsh = (unsigned short*)d_ws;
  float* bg    = (float*)((char*)d_ws + OFF_BG_BYTES);
  float* stage = (float*)((char*)d_ws + OFF_STAGE_BYTES);

  const int B  = in_sizes[0] / HID;   // 32768
  const int NB = B / TB;              // 1024

  hipLaunchKernelGGL(prep_kernel, dim3(512), dim3(256), 0, stream,
                     Wih, Whh, bih, bhh, Wh, Wc, Wo, wsh, bg);

  const size_t stage_need = (size_t)OFF_STAGE_BYTES + (size_t)B * STEPS * INP * 4;
  if (ws_size >= stage_need) {
    hipLaunchKernelGGL((lstm_kernel<1>), dim3(NB), dim3(NTHR), 0, stream,
                       z, wsh, bg, bh, bc, bo, out, stage, NB);
    hipLaunchKernelGGL(reorder_kernel, dim3(B / 8), dim3(512), 0, stream,
                       stage, out, NB);
  } else {
    hipLaunchKernelGGL((lstm_kernel<0>), dim3(NB), dim3(NTHR), 0, stream,
                       z, wsh, bg, bh, bc, bo, out, stage, NB);
  }
}

// Round 2
// 656.202 us; speedup vs baseline: 1.6641x; 1.6641x over previous
//
#include <hip/hip_runtime.h>
#include <hip/hip_bf16.h>

#define HID   256
#define NGATE 1024
#define INP   72
#define INPP  96
#define STEPS 8
#define TB    64
#define LDH   264   // h_lds row stride (bf16 elems): 256 + 8 pad
#define LDX   104   // x_lds row stride: 96 + 8 pad

// ws layout (bf16/ushort element offsets). Regions are the same sizes as the
// strided layout, but each region is now packed in FRAGMENT ORDER: one 512-elem
// (1 KB) block per (wave, quadrant, col-tile, kc) MFMA B-fragment, with the 64
// lanes' 16B slices contiguous at lane*8 elems. Every weight load in the hot
// loop is a fully-coalesced 1KB burst: base(uniform) + lane*16B + const-offset.
#define OFF_WHH 0
#define OFF_WIH 262144   // 1024*256
#define OFF_WH  360448   // + 1024*96
#define OFF_WC  425984   // + 256*256
#define OFF_WO  491520   // + 256*256
#define N_BF    512000   // + 80*256
#define OFF_BG_BYTES 1024000
#define OFF_STAGE_BYTES (1u << 20)   // 1 MiB; y staging buffer lives here

typedef short  s8_t  __attribute__((ext_vector_type(8)));
typedef float  f4_t  __attribute__((ext_vector_type(4)));

static __device__ __forceinline__ unsigned short f2bf(float f) {
  unsigned int u = __float_as_uint(f);
  u = (u + 0x7FFFu + ((u >> 16) & 1u)) >> 16;   // RNE
  return (unsigned short)u;
}
static __device__ __forceinline__ float fast_rcp(float x) {
#if __has_builtin(__builtin_amdgcn_rcpf)
  return __builtin_amdgcn_rcpf(x);   // v_rcp_f32, ~1 ulp
#else
  return 1.f / x;
#endif
}
static __device__ __forceinline__ float sigm(float x) {
  return fast_rcp(1.f + __expf(-x));
}
static __device__ __forceinline__ float tanh_(float x) {
  float t = fminf(-2.f * x, 88.f);
  float e = __expf(t);
  return (1.f - e) * fast_rcp(1.f + e);
}

// Packs weights into fragment-ordered layout.
// Fragment indices (fi, each 512 elems):
//   WHH: fi = w*64 + q*16 + ct*8 + kc        (w<8, q<4, ct<2, kc<8)
//   WIH: fi = w*24 + q*6  + ct*3 + kc        (kc<3)
//   WH : fi = w*16 + ct*8 + kc
//   WC : fi = w*16 + ct*8 + kc
//   WO : fi = yt*8 + kc                       (yt<5)
// Within a fragment, element e = lane*8 + j; lane -> lq = lane>>4, ln = lane&15;
// source col = <wave col base> + ct*16 + ln ; source k = kc*32 + lq*8 + j.
__global__ void prep_kernel(const float* __restrict__ Wih, const float* __restrict__ Whh,
                            const float* __restrict__ bih, const float* __restrict__ bhh,
                            const float* __restrict__ Wh, const float* __restrict__ Wc,
                            const float* __restrict__ Wo,
                            unsigned short* __restrict__ wsh, float* __restrict__ bg) {
  int stride = gridDim.x * blockDim.x;
  for (int i = blockIdx.x * blockDim.x + threadIdx.x; i < N_BF + NGATE; i += stride) {
    if (i < N_BF) {
      int e    = i & 511;
      int fiA  = i >> 9;          // absolute fragment index
      int lane = e >> 3;
      int j    = e & 7;
      int lq   = lane >> 4;       // 0..3  (k-slot)
      int ln   = lane & 15;       // 0..15 (col within tile)
      int kk   = lq * 8 + j;      // k offset within 32-chunk
      float v  = 0.f;
      if (i < OFF_WIH) {
        int fi = fiA;
        int kc = fi & 7, t = fi >> 3, ct = t & 1, u = t >> 1, q = u & 3, w = u >> 2;
        int g  = q * 256 + w * 32 + ct * 16 + ln;
        int k  = kc * 32 + kk;
        v = Whh[g * HID + k];
      } else if (i < OFF_WH) {
        int fi = fiA - (OFF_WIH >> 9);
        int kc = fi % 3, t = fi / 3, ct = t & 1, u = t >> 1, q = u & 3, w = u >> 2;
        int g  = q * 256 + w * 32 + ct * 16 + ln;
        int k  = kc * 32 + kk;
        v = (k < INP) ? Wih[g * INP + k] : 0.f;
      } else if (i < OFF_WC) {
        int fi = fiA - (OFF_WH >> 9);
        int kc = fi & 7, t = fi >> 3, ct = t & 1, w = t >> 1;
        int c  = w * 32 + ct * 16 + ln;
        int k  = kc * 32 + kk;
        v = Wh[c * HID + k];
      } else if (i < OFF_WO) {
        int fi = fiA - (OFF_WC >> 9);
        int kc = fi & 7, t = fi >> 3, ct = t & 1, w = t >> 1;
        int c  = w * 32 + ct * 16 + ln;
        int k  = kc * 32 + kk;
        v = Wc[c * HID + k];
      } else {
        int fi = fiA - (OFF_WO >> 9);
        int kc = fi & 7, yt = fi >> 3;
        int c  = yt * 16 + ln;
        int k  = kc * 32 + kk;
        v = (c < INP) ? Wo[c * HID + k] : 0.f;
      }
      wsh[i] = f2bf(v);
    } else {
      int jb = i - N_BF;
      bg[jb] = bih[jb] + bhh[jb];
    }
  }
}

// Block: 512 threads = 8 waves, owns TB=64 batch rows for the whole recurrence.
// Wave w owns gate cols [w*32, w*32+32) inside EACH of the 4 gate quadrants ->
// lane-local LSTM cell update; c state lives in registers across all 8 steps.
// Weight fragments are pre-packed (see prep_kernel): every B-frag load is a
// fully-coalesced 1KB burst at wave_base + lane*16B + compile-time offset.
template <int STAGED>
__global__ __launch_bounds__(512, 2) void lstm_kernel(
    const float* __restrict__ z, const unsigned short* __restrict__ wsh,
    const float* __restrict__ bg, const float* __restrict__ bh,
    const float* __restrict__ bc, const float* __restrict__ bo,
    float* __restrict__ out, float* __restrict__ stage, int NB) {
  __shared__ unsigned short h_lds[TB * LDH];
  __shared__ unsigned short x_lds[TB * LDX];

  const int tid  = threadIdx.x;
  const int w    = tid >> 6;     // wave 0..7
  const int lane = tid & 63;
  const int lq   = lane >> 4;    // quad 0..3
  const int ln   = lane & 15;
  const int rb   = blockIdx.x * TB;
  const int colh0 = w * 32 + ln; // wave's hidden-col base (+ct*16)

  // packed fragment bases: uniform-per-wave + lane*8 elems (16B/lane)
  const unsigned short* whh_l = wsh + OFF_WHH + w * 32768 + lane * 8;
  const unsigned short* wih_l = wsh + OFF_WIH + w * 12288 + lane * 8;
  const unsigned short* wh_l  = wsh + OFF_WH  + w * 8192  + lane * 8;
  const unsigned short* wc_l  = wsh + OFF_WC  + w * 8192  + lane * 8;
  const unsigned short* h_rd  = &h_lds[ln * LDH + lq * 8];
  const unsigned short* x_rd  = &x_lds[ln * LDX + lq * 8];
  unsigned short*       h_wr  = &h_lds[(lq * 4) * LDH + colh0];

  // x starts as zeros (incl. pad cols 72..95)
  for (int i = tid; i < TB * LDX; i += 512) x_lds[i] = 0;

  // ---------------- init: h = z0@Wh^T + bh, c = z0@Wc^T + bc ----------------
  f4_t acc_h[4][2], acc_c[4][2];
  #pragma unroll
  for (int rt = 0; rt < 4; ++rt)
    #pragma unroll
    for (int ct = 0; ct < 2; ++ct) {
      acc_h[rt][ct] = {0.f, 0.f, 0.f, 0.f};
      acc_c[rt][ct] = {0.f, 0.f, 0.f, 0.f};
    }

  const float* z_l = z + (size_t)(rb + ln) * HID + lq * 8;

  #pragma unroll 2
  for (int kc = 0; kc < 8; ++kc) {
    s8_t a[4];
    #pragma unroll
    for (int rt = 0; rt < 4; ++rt) {
      f4_t v0 = *reinterpret_cast<const f4_t*>(z_l + rt * 16 * HID + kc * 32);
      f4_t v1 = *reinterpret_cast<const f4_t*>(z_l + rt * 16 * HID + kc * 32 + 4);
      s8_t av;
      av[0] = (short)f2bf(v0[0]); av[1] = (short)f2bf(v0[1]);
      av[2] = (short)f2bf(v0[2]); av[3] = (short)f2bf(v0[3]);
      av[4] = (short)f2bf(v1[0]); av[5] = (short)f2bf(v1[1]);
      av[6] = (short)f2bf(v1[2]); av[7] = (short)f2bf(v1[3]);
      a[rt] = av;
    }
    #pragma unroll
    for (int ct = 0; ct < 2; ++ct) {
      s8_t bhf = *reinterpret_cast<const s8_t*>(wh_l + (ct * 8 + kc) * 512);
      s8_t bcf = *reinterpret_cast<const s8_t*>(wc_l + (ct * 8 + kc) * 512);
      #pragma unroll
      for (int rt = 0; rt < 4; ++rt) {
        acc_h[rt][ct] = __builtin_amdgcn_mfma_f32_16x16x32_bf16(a[rt], bhf, acc_h[rt][ct], 0, 0, 0);
        acc_c[rt][ct] = __builtin_amdgcn_mfma_f32_16x16x32_bf16(a[rt], bcf, acc_c[rt][ct], 0, 0, 0);
      }
    }
  }

  float c_reg[4][2][4];
  #pragma unroll
  for (int ct = 0; ct < 2; ++ct) {
    const float bhv = bh[colh0 + ct * 16];
    const float bcv = bc[colh0 + ct * 16];
    #pragma unroll
    for (int rt = 0; rt < 4; ++rt)
      #pragma unroll
      for (int r = 0; r < 4; ++r) {
        float hv = acc_h[rt][ct][r] + bhv;
        c_reg[rt][ct][r] = acc_c[rt][ct][r] + bcv;
        h_wr[(rt * 16 + r) * LDH + ct * 16] = f2bf(hv);
      }
  }
  __syncthreads();

  float biasg[4][2];
  #pragma unroll
  for (int q = 0; q < 4; ++q)
    #pragma unroll
    for (int ct = 0; ct < 2; ++ct)
      biasg[q][ct] = bg[q * 256 + colh0 + ct * 16];

  const int colY = w * 16 + ln;            // y col, valid for waves 0..4
  float bov = 0.f;
  const unsigned short* wo_l = wsh + OFF_WO + (w < 5 ? w : 0) * 4096 + lane * 8;
  if (w < 5) {
    if (colY < INP) bov = bo[colY];
  }

  for (int s = 0; s < STEPS; ++s) {
    f4_t acc[4][4][2];                     // [quadrant][row-tile][col-tile]
    #pragma unroll
    for (int q = 0; q < 4; ++q)
      #pragma unroll
      for (int rt = 0; rt < 4; ++rt)
        #pragma unroll
        for (int ct = 0; ct < 2; ++ct) {
          const float b = biasg[q][ct];
          acc[q][rt][ct] = {b, b, b, b};
        }

    // gates += h @ W_hh^T   (K = 256)
    #pragma unroll 2
    for (int kc = 0; kc < 8; ++kc) {
      s8_t a[4];
      #pragma unroll
      for (int rt = 0; rt < 4; ++rt)
        a[rt] = *reinterpret_cast<const s8_t*>(h_rd + rt * 16 * LDH + kc * 32);
      #pragma unroll
      for (int q = 0; q < 4; ++q)
        #pragma unroll
        for (int ct = 0; ct < 2; ++ct) {
          s8_t bfr = *reinterpret_cast<const s8_t*>(whh_l + (q * 16 + ct * 8 + kc) * 512);
          #pragma unroll
          for (int rt = 0; rt < 4; ++rt)
            acc[q][rt][ct] = __builtin_amdgcn_mfma_f32_16x16x32_bf16(a[rt], bfr, acc[q][rt][ct], 0, 0, 0);
        }
    }
    // gates += x @ W_ih^T   (K = 96 padded, x pad cols are zero)
    #pragma unroll
    for (int kc = 0; kc < 3; ++kc) {
      s8_t a[4];
      #pragma unroll
      for (int rt = 0; rt < 4; ++rt)
        a[rt] = *reinterpret_cast<const s8_t*>(x_rd + rt * 16 * LDX + kc * 32);
      #pragma unroll
      for (int q = 0; q < 4; ++q)
        #pragma unroll
        for (int ct = 0; ct < 2; ++ct) {
          s8_t bfr = *reinterpret_cast<const s8_t*>(wih_l + (q * 6 + ct * 3 + kc) * 512);
          #pragma unroll
          for (int rt = 0; rt < 4; ++rt)
            acc[q][rt][ct] = __builtin_amdgcn_mfma_f32_16x16x32_bf16(a[rt], bfr, acc[q][rt][ct], 0, 0, 0);
        }
    }
    __syncthreads();   // all h_lds/x_lds reads done

    // lane-local LSTM cell update; write new h (bf16) to LDS
    #pragma unroll
    for (int rt = 0; rt < 4; ++rt)
      #pragma unroll
      for (int ct = 0; ct < 2; ++ct)
        #pragma unroll
        for (int r = 0; r < 4; ++r) {
          float iv = sigm(acc[0][rt][ct][r]);
          float fv = sigm(acc[1][rt][ct][r]);
          float gv = tanh_(acc[2][rt][ct][r]);
          float ov = sigm(acc[3][rt][ct][r]);
          float cn = fv * c_reg[rt][ct][r] + iv * gv;
          c_reg[rt][ct][r] = cn;
          float hv = ov * tanh_(cn);
          h_wr[(rt * 16 + r) * LDH + ct * 16] = f2bf(hv);
        }
    __syncthreads();   // new h visible to all waves

    // y = sigmoid(h_new @ Wo^T + bo); store (staged or direct), feed back as x
    if (w < 5) {
      f4_t accy[4];
      #pragma unroll
      for (int rt = 0; rt < 4; ++rt) accy[rt] = {bov, bov, bov, bov};
      #pragma unroll 2
      for (int kc = 0; kc < 8; ++kc) {
        s8_t bfr = *reinterpret_cast<const s8_t*>(wo_l + kc * 512);
        #pragma unroll
        for (int rt = 0; rt < 4; ++rt) {
          s8_t a = *reinterpret_cast<const s8_t*>(h_rd + rt * 16 * LDH + kc * 32);
          accy[rt] = __builtin_amdgcn_mfma_f32_16x16x32_bf16(a, bfr, accy[rt], 0, 0, 0);
        }
      }
      if (colY < INP) {
        float* st_base;
        if (STAGED) {
          st_base = stage + (((size_t)s * NB + blockIdx.x) * TB + lq * 4) * INP + colY;
        } else {
          st_base = out + (size_t)(rb + lq * 4) * (STEPS * INP) + s * INP + colY;
        }
        unsigned short* x_wr = &x_lds[(lq * 4) * LDX + colY];
        #pragma unroll
        for (int rt = 0; rt < 4; ++rt)
          #pragma unroll
          for (int r = 0; r < 4; ++r) {
            float yv = sigm(accy[rt][r]);
            if (STAGED) {
              st_base[(size_t)(rt * 16 + r) * INP] = yv;
            } else {
              st_base[(size_t)(rt * 16 + r) * (STEPS * INP)] = yv;
            }
            x_wr[(rt * 16 + r) * LDX] = f2bf(yv);
          }
      }
    }
    __syncthreads();   // x_lds writes done before next step's reads
  }
}

// stage[((s*NB + b)*TB + r)*72 + c]  ->  out[(b*TB + r)*576 + s*72 + c]
__global__ __launch_bounds__(512) void reorder_kernel(
    const float* __restrict__ stage, float* __restrict__ out, int NB) {
  const int lane = threadIdx.x & 63;
  const int row  = blockIdx.x * 8 + (threadIdx.x >> 6);   // global batch row
  const int b    = row >> 6;          // TB=64
  const int r    = row & 63;
  #pragma unroll
  for (int i = lane; i < STEPS * INP; i += 64) {
    int s = i / INP;
    int c = i - s * INP;
    out[(size_t)row * (STEPS * INP) + i] =
        stage[(((size_t)s * NB + b) * TB + r) * INP + c];
  }
}

extern "C" void kernel_launch(void* const* d_in, const int* in_sizes, int n_in,
                              void* d_out, int out_size, void* d_ws, size_t ws_size,
                              hipStream_t stream) {
  const float* z   = (const float*)d_in[0];
  const float* Wih = (const float*)d_in[1];
  const float* Whh = (const float*)d_in[2];
  const float* bih = (const float*)d_in[3];
  const float* bhh = (const float*)d_in[4];
  const float* Wh  = (const float*)d_in[5];
  const float* bh  = (const float*)d_in[6];
  const float* Wc  = (const float*)d_in[7];
  const float* bc  = (const float*)d_in[8];
  const float* Wo  = (const float*)d_in[9];
  const float* bo  = (const float*)d_in[10];
  float* out = (float*)d_out;

  unsigned short* wsh = (unsigned short*)d_ws;
  float* bg    = (float*)((char*)d_ws + OFF_BG_BYTES);
  float* stage = (float*)((char*)d_ws + OFF_STAGE_BYTES);

  const int B  = in_sizes[0] / HID;   // 32768
  const int NB = B / TB;              // 512

  hipLaunchKernelGGL(prep_kernel, dim3(512), dim3(256), 0, stream,
                     Wih, Whh, bih, bhh, Wh, Wc, Wo, wsh, bg);

  const size_t stage_need = (size_t)OFF_STAGE_BYTES + (size_t)B * STEPS * INP * 4;
  if (ws_size >= stage_need) {
    hipLaunchKernelGGL((lstm_kernel<1>), dim3(NB), dim3(512), 0, stream,
                       z, wsh, bg, bh, bc, bo, out, stage, NB);
    hipLaunchKernelGGL(reorder_kernel, dim3(B / 8), dim3(512), 0, stream,
                       stage, out, NB);
  } else {
    hipLaunchKernelGGL((lstm_kernel<0>), dim3(NB), dim3(512), 0, stream,
                       z, wsh, bg, bh, bc, bo, out, stage, NB);
  }
}